// Round 17
// baseline (38.006 us; speedup 1.0000x reference)
//
#include <hip/hip_runtime.h>

#define BATCH 4
#define NPTS 8192
#define PTOT (BATCH * NPTS)   // 32768 points per cloud
#define NJH 16                // ref-range splits
#define TILES (NPTS / 32 / NJH)   // 16 ref-tiles per jh range (16 KB LDS)

typedef __attribute__((ext_vector_type(8))) short short8;     // 8 bf16 = 4 VGPRs
typedef __attribute__((ext_vector_type(16))) float f32x16;    // MFMA 32x32 accumulator

__device__ __forceinline__ ushort f2bf(float f) {             // RNE float->bf16 bits
    unsigned u = __float_as_uint(f);
    unsigned r = (u + 0x7fffu + ((u >> 16) & 1u)) >> 16;
    return (ushort)r;
}
__device__ __forceinline__ float bf2f(ushort b) {
    return __uint_as_float(((unsigned)b) << 16);
}

// 8-min3 tree: fold 16 MFMA outputs + carry into one scalar (fminf pairs
// fuse to v_min3_f32).  Plain C++ only — R13: inline-asm reads of MFMA
// results race the MFMA write (no hazard nops inserted for asm consumers).
__device__ __forceinline__ float tree16(const f32x16 a, float run) {
    float m0 = fminf(fminf(a[0],  a[1]),  a[2]);
    float m1 = fminf(fminf(a[3],  a[4]),  a[5]);
    float m2 = fminf(fminf(a[6],  a[7]),  a[8]);
    float m3 = fminf(fminf(a[9],  a[10]), a[11]);
    float m4 = fminf(fminf(a[12], a[13]), a[14]);
    float n0 = fminf(fminf(m0, m1), m2);
    float n1 = fminf(fminf(m3, m4), a[15]);
    return fminf(run, fminf(n0, n1));
}

// ---------------------------------------------------------------------------
// k-order (Q row must match R's subtiled khalf split):
//   k 0..5 : Q = ch0,ch1,ch2, cl0,cl1,cl2      R = mh0,mh1,mh2, mh0,mh1,mh2
//   k 6..7 : Q = n2h, n2l                       R = ONE, ONE
//   k 8..13: Q = ch0,ch1,ch2, cl0,cl1,cl2      R = ml0,ml1,ml2, ml0,ml1,ml2
//   k14..15: Q = ONE, ONE                       R = n2h, n2l
// Q_n . R_m = -2*(xh+xl).(yh+yl) + x2 + y2 ~= ||x-y||^2 (products exact).
// Qpan: [cloud][PTOT][16] row-major. Rpan: [cloud][batch][tile][khalf][col][8].
// ---------------------------------------------------------------------------
__global__ __launch_bounds__(256) void pack_k(const float* __restrict__ pred,
                                              const float* __restrict__ tgt,
                                              ushort* __restrict__ Qpan,
                                              ushort* __restrict__ Rpan,
                                              int* __restrict__ counter) {
    int i = blockIdx.x * 256 + threadIdx.x;      // [0, 2*PTOT), cloud-major
    if (i == 0) *counter = 0;                    // reset last-block ticket
    int cloud = (i >= PTOT) ? 1 : 0;
    int jg = cloud ? i - PTOT : i;               // [0, PTOT)
    const float* s = cloud ? tgt : pred;
    float c0 = s[3 * jg + 0], c1 = s[3 * jg + 1], c2 = s[3 * jg + 2];
    float c[3] = {c0, c1, c2};
    ushort hh[3], ll[3], mh[3], ml[3];
#pragma unroll
    for (int d = 0; d < 3; ++d) {
        ushort h = f2bf(c[d]); float hf = bf2f(h);
        ushort l = f2bf(c[d] - hf); float lf = bf2f(l);   // exact residual split
        hh[d] = h; ll[d] = l;
        mh[d] = f2bf(-2.0f * hf);                         // exact (pow2 scale)
        ml[d] = f2bf(-2.0f * lf);
    }
    float n2 = fmaf(c0, c0, fmaf(c1, c1, c2 * c2));
    ushort n2h = f2bf(n2);
    ushort n2l = f2bf(n2 - bf2f(n2h));
    const ushort ONE = 0x3F80;

    __attribute__((aligned(16))) ushort a[16] = {
        hh[0], hh[1], hh[2], ll[0], ll[1], ll[2], n2h, n2l,
        hh[0], hh[1], hh[2], ll[0], ll[1], ll[2], ONE, ONE};
    __attribute__((aligned(16))) ushort blo[8] = {
        mh[0], mh[1], mh[2], mh[0], mh[1], mh[2], ONE, ONE};   // k = 0..7
    __attribute__((aligned(16))) ushort bhi[8] = {
        ml[0], ml[1], ml[2], ml[0], ml[1], ml[2], n2h, n2l};   // k = 8..15

    ushort* ad = Qpan + (size_t)i * 16;
    *(uint4*)ad       = *(const uint4*)a;
    *(uint4*)(ad + 8) = *(const uint4*)(a + 8);

    int loc = jg & (NPTS - 1);
    int t   = loc >> 5;
    int col = loc & 31;
    size_t bb = ((size_t)cloud * PTOT + (size_t)(jg >> 13) * NPTS) * 16
              + (size_t)t * 512 + (size_t)col * 8;
    *(uint4*)(Rpan + bb)       = *(const uint4*)blo;   // khalf 0
    *(uint4*)(Rpan + bb + 256) = *(const uint4*)bhi;   // khalf 1
}

// ---------------------------------------------------------------------------
// Grid: 2048 blocks = jh(16) x dir(2) x batch(4) x qblk(16); 512 thr (8 waves).
// __launch_bounds__(512, 6): 85-reg cap -> 3 blocks/CU co-resident (better
// tail balance + latency hiding than R15's 2/CU at the 128 cap).
// Block stages its 16-tile ref panel (16 KB) into LDS once. Each wave: 64
// queries (2 B-frags); per ref-tile: 1 ds_read_b128 -> 2 MFMA -> 2 tree16.
// s_setprio(1) around the compute loop (T5: waves are desynced; MFMA-phase
// waves win issue arbitration over staging-phase waves of other blocks).
// Min is lane-local (C col=lane=query). part layout: [jh][dir][batch][NPTS].
// ---------------------------------------------------------------------------
__global__ __launch_bounds__(512, 6) void chamfer_mfma_k(const ushort* __restrict__ Qpan,
                                                         const ushort* __restrict__ Rpan,
                                                         float* __restrict__ part) {
    __shared__ ushort Rsm[TILES * 512];   // 16 KB

    int bid  = blockIdx.x;
    int qblk = bid & 15;
    int b    = (bid >> 4) & 3;
    int dir  = (bid >> 6) & 1;
    int jh   = bid >> 7;           // 0..15
    int tid  = threadIdx.x;
    int lane = tid & 63;
    int wave = tid >> 6;           // 0..7

    const ushort* Qp = Qpan + ((size_t)dir * PTOT + (size_t)b * NPTS) * 16;
    const ushort* Rp = Rpan + ((size_t)(1 - dir) * PTOT + (size_t)b * NPTS) * 16
                            + (size_t)jh * TILES * 512;

    // stage ref panel: 16 KB = 1024 float4, 512 threads x 2 iters (coalesced)
    {
        const float4* src = (const float4*)Rp;
        float4* dst = (float4*)Rsm;
        dst[tid]       = src[tid];
        dst[512 + tid] = src[512 + tid];
    }

    // Q frags (global, L2-resident): qf0 -> cols q..q+31, qf1 -> q+32..q+63
    int q = qblk * 512 + wave * 64;
    const short8 qf0 = *reinterpret_cast<const short8*>(
        Qp + (size_t)(q + (lane & 31)) * 16 + 8 * (lane >> 5));
    const short8 qf1 = *reinterpret_cast<const short8*>(
        Qp + (size_t)(q + 32 + (lane & 31)) * 16 + 8 * (lane >> 5));

    __syncthreads();

    // ref frag in LDS: tile t -> t*512 + (lane>>5)*256 + (lane&31)*8 (ushorts)
    const ushort* rbase = Rsm + (size_t)(lane >> 5) * 256 + (size_t)(lane & 31) * 8;

    f32x16 zero = {};
    float run0 = 1e30f, run1 = 1e30f;

    __builtin_amdgcn_s_setprio(1);
#pragma unroll 8
    for (int t = 0; t < TILES; ++t) {
        short8 r = *reinterpret_cast<const short8*>(rbase + (size_t)t * 512);
        f32x16 a0 = __builtin_amdgcn_mfma_f32_32x32x16_bf16(r, qf0, zero, 0, 0, 0);
        f32x16 a1 = __builtin_amdgcn_mfma_f32_32x32x16_bf16(r, qf1, zero, 0, 0, 0);
        run0 = tree16(a0, run0);
        run1 = tree16(a1, run1);
    }
    __builtin_amdgcn_s_setprio(0);

    // rows split across lane halves (row has +4*(lane>>5)): combine halves
    run0 = fminf(run0, __shfl_xor(run0, 32, 64));
    run1 = fminf(run1, __shfl_xor(run1, 32, 64));
    // lanes 0..31: queries q..q+31 (run0); lanes 32..63: q+32..q+63 (run1)
    size_t pbase = (((size_t)jh * 2 + dir) * BATCH + b) * NPTS;
    part[pbase + q + lane] = (lane < 32) ? run0 : run1;
}

// Fused reduction: 256 blocks. Each block: min over NJH splits, clamp,
// block-sum -> bsum[bid]; the LAST block (device-scope ticket) then reduces
// bsum[0..255] in fixed index order (deterministic) and writes the output.
__global__ __launch_bounds__(256) void reduce_k(const float* __restrict__ part,
                                                float* __restrict__ bsum,
                                                int* __restrict__ counter,
                                                float* __restrict__ out) {
    int q = blockIdx.x * 256 + threadIdx.x;   // [0, 65536)
    float v = part[q];
#pragma unroll
    for (int jh = 1; jh < NJH; ++jh)
        v = fminf(v, part[(size_t)jh * 65536 + q]);
    v = fmaxf(v, 0.0f);
    for (int off = 32; off; off >>= 1) v += __shfl_down(v, off, 64);
    __shared__ float lds[4];
    __shared__ int ticket_s;
    int lane = threadIdx.x & 63, w = threadIdx.x >> 6;
    if (lane == 0) lds[w] = v;
    __syncthreads();
    if (threadIdx.x == 0) {
        bsum[blockIdx.x] = (lds[0] + lds[1]) + (lds[2] + lds[3]);
        __threadfence();                       // publish bsum before ticket
        ticket_s = atomicAdd(counter, 1);
    }
    __syncthreads();
    if (ticket_s == 255) {                     // last block finishes the sum
        __threadfence();                       // acquire all bsum writes
        float s = bsum[threadIdx.x];
        for (int off = 32; off; off >>= 1) s += __shfl_down(s, off, 64);
        __syncthreads();                       // lds reuse
        if (lane == 0) lds[w] = s;
        __syncthreads();
        if (threadIdx.x == 0)
            out[0] = ((lds[0] + lds[1]) + (lds[2] + lds[3])) * (1.0f / 32768.0f);
    }
}

extern "C" void kernel_launch(void* const* d_in, const int* in_sizes, int n_in,
                              void* d_out, int out_size, void* d_ws, size_t ws_size,
                              hipStream_t stream) {
    const float* pred = (const float*)d_in[0];
    const float* tgt  = (const float*)d_in[1];

    ushort* Qpan = (ushort*)d_ws;                          // 2 MB
    ushort* Rpan = Qpan + (size_t)2 * PTOT * 16;           // 2 MB
    float*  part = (float*)(Rpan + (size_t)2 * PTOT * 16); // NJH*2*PTOT floats = 4 MB
    float*  bsum = part + (size_t)NJH * 2 * PTOT;          // 256 floats
    int*    counter = (int*)(bsum + 256);                  // 1 int (ticket)

    pack_k<<<(2 * PTOT) / 256, 256, 0, stream>>>(pred, tgt, Qpan, Rpan, counter);
    chamfer_mfma_k<<<NJH * 2 * BATCH * 16, 512, 0, stream>>>(Qpan, Rpan, part);
    reduce_k<<<256, 256, 0, stream>>>(part, bsum, counter, (float*)d_out);
}

// Round 18
// 35.908 us; speedup vs baseline: 1.0584x; 1.0584x over previous
//
#include <hip/hip_runtime.h>

#define BATCH 4
#define NPTS 8192
#define PTOT (BATCH * NPTS)   // 32768 points per cloud
#define NJH 8                 // ref-range splits
#define TILES (NPTS / 32 / NJH)   // 32 ref-tiles per jh range (32 KB LDS)

typedef __attribute__((ext_vector_type(8))) short short8;     // 8 bf16 = 4 VGPRs
typedef __attribute__((ext_vector_type(16))) float f32x16;    // MFMA 32x32 accumulator

__device__ __forceinline__ ushort f2bf(float f) {             // RNE float->bf16 bits
    unsigned u = __float_as_uint(f);
    unsigned r = (u + 0x7fffu + ((u >> 16) & 1u)) >> 16;
    return (ushort)r;
}
__device__ __forceinline__ float bf2f(ushort b) {
    return __uint_as_float(((unsigned)b) << 16);
}

// 8-min3 tree: fold 16 MFMA outputs + carry into one scalar (fminf pairs
// fuse to v_min3_f32).  Plain C++ only — R13: inline-asm reads of MFMA
// results race the MFMA write (no hazard nops inserted for asm consumers).
__device__ __forceinline__ float tree16(const f32x16 a, float run) {
    float m0 = fminf(fminf(a[0],  a[1]),  a[2]);
    float m1 = fminf(fminf(a[3],  a[4]),  a[5]);
    float m2 = fminf(fminf(a[6],  a[7]),  a[8]);
    float m3 = fminf(fminf(a[9],  a[10]), a[11]);
    float m4 = fminf(fminf(a[12], a[13]), a[14]);
    float n0 = fminf(fminf(m0, m1), m2);
    float n1 = fminf(fminf(m3, m4), a[15]);
    return fminf(run, fminf(n0, n1));
}

// ---------------------------------------------------------------------------
// k-order (Q row must match R's subtiled khalf split):
//   k 0..5 : Q = ch0,ch1,ch2, cl0,cl1,cl2      R = mh0,mh1,mh2, mh0,mh1,mh2
//   k 6..7 : Q = n2h, n2l                       R = ONE, ONE
//   k 8..13: Q = ch0,ch1,ch2, cl0,cl1,cl2      R = ml0,ml1,ml2, ml0,ml1,ml2
//   k14..15: Q = ONE, ONE                       R = n2h, n2l
// Q_n . R_m = -2*(xh+xl).(yh+yl) + x2 + y2 ~= ||x-y||^2 (products exact;
// only hi/lo split residual ~2^-17 remains). Refs feed the MFMA A slot
// (lane-local min over C rows), queries the B slot (col=lane).
// Qpan: [cloud][PTOT][16] row-major. Rpan: [cloud][batch][tile][khalf][col][8].
// ---------------------------------------------------------------------------
__global__ __launch_bounds__(256) void pack_k(const float* __restrict__ pred,
                                              const float* __restrict__ tgt,
                                              ushort* __restrict__ Qpan,
                                              ushort* __restrict__ Rpan,
                                              int* __restrict__ counter) {
    int i = blockIdx.x * 256 + threadIdx.x;      // [0, 2*PTOT), cloud-major
    if (i == 0) *counter = 0;                    // reset last-block ticket
    int cloud = (i >= PTOT) ? 1 : 0;
    int jg = cloud ? i - PTOT : i;               // [0, PTOT)
    const float* s = cloud ? tgt : pred;
    float c0 = s[3 * jg + 0], c1 = s[3 * jg + 1], c2 = s[3 * jg + 2];
    float c[3] = {c0, c1, c2};
    ushort hh[3], ll[3], mh[3], ml[3];
#pragma unroll
    for (int d = 0; d < 3; ++d) {
        ushort h = f2bf(c[d]); float hf = bf2f(h);
        ushort l = f2bf(c[d] - hf); float lf = bf2f(l);   // exact residual split
        hh[d] = h; ll[d] = l;
        mh[d] = f2bf(-2.0f * hf);                         // exact (pow2 scale)
        ml[d] = f2bf(-2.0f * lf);
    }
    float n2 = fmaf(c0, c0, fmaf(c1, c1, c2 * c2));
    ushort n2h = f2bf(n2);
    ushort n2l = f2bf(n2 - bf2f(n2h));
    const ushort ONE = 0x3F80;

    __attribute__((aligned(16))) ushort a[16] = {
        hh[0], hh[1], hh[2], ll[0], ll[1], ll[2], n2h, n2l,
        hh[0], hh[1], hh[2], ll[0], ll[1], ll[2], ONE, ONE};
    __attribute__((aligned(16))) ushort blo[8] = {
        mh[0], mh[1], mh[2], mh[0], mh[1], mh[2], ONE, ONE};   // k = 0..7
    __attribute__((aligned(16))) ushort bhi[8] = {
        ml[0], ml[1], ml[2], ml[0], ml[1], ml[2], n2h, n2l};   // k = 8..15

    ushort* ad = Qpan + (size_t)i * 16;
    *(uint4*)ad       = *(const uint4*)a;
    *(uint4*)(ad + 8) = *(const uint4*)(a + 8);

    int loc = jg & (NPTS - 1);
    int t   = loc >> 5;
    int col = loc & 31;
    size_t bb = ((size_t)cloud * PTOT + (size_t)(jg >> 13) * NPTS) * 16
              + (size_t)t * 512 + (size_t)col * 8;
    *(uint4*)(Rpan + bb)       = *(const uint4*)blo;   // khalf 0
    *(uint4*)(Rpan + bb + 256) = *(const uint4*)bhi;   // khalf 1
}

// ---------------------------------------------------------------------------
// R15's proven config (best measured: 31.18us total, steady ~17.4us).
// Grid: 1024 blocks = jh(8) x dir(2) x batch(4) x qblk(16); 512 thr (8 waves).
// __launch_bounds__(512, 4): 128-reg cap, no spills, 2 blocks/CU.
// Block stages its 32-tile ref panel (32 KB) into LDS once. Each wave: 64
// queries (2 B-frags); per ref-tile: 1 ds_read_b128 -> 2 MFMA -> 2 tree16.
// Min is lane-local (C col=lane=query). part layout: [jh][dir][batch][NPTS].
// ---------------------------------------------------------------------------
__global__ __launch_bounds__(512, 4) void chamfer_mfma_k(const ushort* __restrict__ Qpan,
                                                         const ushort* __restrict__ Rpan,
                                                         float* __restrict__ part) {
    __shared__ ushort Rsm[TILES * 512];   // 32 KB

    int bid  = blockIdx.x;
    int qblk = bid & 15;
    int b    = (bid >> 4) & 3;
    int dir  = (bid >> 6) & 1;
    int jh   = bid >> 7;           // 0..7
    int tid  = threadIdx.x;
    int lane = tid & 63;
    int wave = tid >> 6;           // 0..7

    const ushort* Qp = Qpan + ((size_t)dir * PTOT + (size_t)b * NPTS) * 16;
    const ushort* Rp = Rpan + ((size_t)(1 - dir) * PTOT + (size_t)b * NPTS) * 16
                            + (size_t)jh * TILES * 512;

    // stage ref panel: 32 KB = 2048 float4, 512 threads x 4 iters (coalesced)
    {
        const float4* src = (const float4*)Rp;
        float4* dst = (float4*)Rsm;
#pragma unroll
        for (int it = 0; it < 4; ++it)
            dst[it * 512 + tid] = src[it * 512 + tid];
    }

    // Q frags (global, L2-resident): qf0 -> cols q..q+31, qf1 -> q+32..q+63
    int q = qblk * 512 + wave * 64;
    const short8 qf0 = *reinterpret_cast<const short8*>(
        Qp + (size_t)(q + (lane & 31)) * 16 + 8 * (lane >> 5));
    const short8 qf1 = *reinterpret_cast<const short8*>(
        Qp + (size_t)(q + 32 + (lane & 31)) * 16 + 8 * (lane >> 5));

    __syncthreads();

    // ref frag in LDS: tile t -> t*512 + (lane>>5)*256 + (lane&31)*8 (ushorts)
    const ushort* rbase = Rsm + (size_t)(lane >> 5) * 256 + (size_t)(lane & 31) * 8;

    f32x16 zero = {};
    float run0 = 1e30f, run1 = 1e30f;

#pragma unroll 8
    for (int t = 0; t < TILES; ++t) {
        short8 r = *reinterpret_cast<const short8*>(rbase + (size_t)t * 512);
        f32x16 a0 = __builtin_amdgcn_mfma_f32_32x32x16_bf16(r, qf0, zero, 0, 0, 0);
        f32x16 a1 = __builtin_amdgcn_mfma_f32_32x32x16_bf16(r, qf1, zero, 0, 0, 0);
        run0 = tree16(a0, run0);
        run1 = tree16(a1, run1);
    }

    // rows split across lane halves (row has +4*(lane>>5)): combine halves
    run0 = fminf(run0, __shfl_xor(run0, 32, 64));
    run1 = fminf(run1, __shfl_xor(run1, 32, 64));
    // lanes 0..31: queries q..q+31 (run0); lanes 32..63: q+32..q+63 (run1)
    size_t pbase = (((size_t)jh * 2 + dir) * BATCH + b) * NPTS;
    part[pbase + q + lane] = (lane < 32) ? run0 : run1;
}

// Fused reduction (proven correct in R17): 256 blocks. Each block: min over
// NJH splits, clamp, block-sum -> bsum[bid]; the LAST block (device-scope
// ticket) reduces bsum[0..255] in fixed index order and writes the output.
__global__ __launch_bounds__(256) void reduce_k(const float* __restrict__ part,
                                                float* __restrict__ bsum,
                                                int* __restrict__ counter,
                                                float* __restrict__ out) {
    int q = blockIdx.x * 256 + threadIdx.x;   // [0, 65536)
    float v = part[q];
#pragma unroll
    for (int jh = 1; jh < NJH; ++jh)
        v = fminf(v, part[(size_t)jh * 65536 + q]);
    v = fmaxf(v, 0.0f);
    for (int off = 32; off; off >>= 1) v += __shfl_down(v, off, 64);
    __shared__ float lds[4];
    __shared__ int ticket_s;
    int lane = threadIdx.x & 63, w = threadIdx.x >> 6;
    if (lane == 0) lds[w] = v;
    __syncthreads();
    if (threadIdx.x == 0) {
        bsum[blockIdx.x] = (lds[0] + lds[1]) + (lds[2] + lds[3]);
        __threadfence();                       // publish bsum before ticket
        ticket_s = atomicAdd(counter, 1);
    }
    __syncthreads();
    if (ticket_s == 255) {                     // last block finishes the sum
        __threadfence();                       // acquire all bsum writes
        float s = bsum[threadIdx.x];
        for (int off = 32; off; off >>= 1) s += __shfl_down(s, off, 64);
        __syncthreads();                       // lds reuse
        if (lane == 0) lds[w] = s;
        __syncthreads();
        if (threadIdx.x == 0)
            out[0] = ((lds[0] + lds[1]) + (lds[2] + lds[3])) * (1.0f / 32768.0f);
    }
}

extern "C" void kernel_launch(void* const* d_in, const int* in_sizes, int n_in,
                              void* d_out, int out_size, void* d_ws, size_t ws_size,
                              hipStream_t stream) {
    const float* pred = (const float*)d_in[0];
    const float* tgt  = (const float*)d_in[1];

    ushort* Qpan = (ushort*)d_ws;                          // 2 MB
    ushort* Rpan = Qpan + (size_t)2 * PTOT * 16;           // 2 MB
    float*  part = (float*)(Rpan + (size_t)2 * PTOT * 16); // NJH*2*PTOT floats = 2 MB
    float*  bsum = part + (size_t)NJH * 2 * PTOT;          // 256 floats
    int*    counter = (int*)(bsum + 256);                  // 1 int (ticket)

    pack_k<<<(2 * PTOT) / 256, 256, 0, stream>>>(pred, tgt, Qpan, Rpan, counter);
    chamfer_mfma_k<<<NJH * 2 * BATCH * 16, 512, 0, stream>>>(Qpan, Rpan, part);
    reduce_k<<<256, 256, 0, stream>>>(part, bsum, counter, (float*)d_out);
}

// Round 19
// 31.164 us; speedup vs baseline: 1.2196x; 1.1522x over previous
//
#include <hip/hip_runtime.h>

#define BATCH 4
#define NPTS 8192
#define PTOT (BATCH * NPTS)   // 32768 points per cloud
#define NJH 8                 // ref-range splits
#define TILES (NPTS / 32 / NJH)   // 32 ref-tiles per jh range (32 KB LDS)

typedef __attribute__((ext_vector_type(8))) short short8;     // 8 bf16 = 4 VGPRs
typedef __attribute__((ext_vector_type(16))) float f32x16;    // MFMA 32x32 accumulator

__device__ __forceinline__ ushort f2bf(float f) {             // RNE float->bf16 bits
    unsigned u = __float_as_uint(f);
    unsigned r = (u + 0x7fffu + ((u >> 16) & 1u)) >> 16;
    return (ushort)r;
}
__device__ __forceinline__ float bf2f(ushort b) {
    return __uint_as_float(((unsigned)b) << 16);
}

// 8-min3 tree: fold 16 MFMA outputs + carry into one scalar (fminf pairs
// fuse to v_min3_f32).  Plain C++ only — R13: inline-asm reads of MFMA
// results race the MFMA write (no hazard nops inserted for asm consumers).
__device__ __forceinline__ float tree16(const f32x16 a, float run) {
    float m0 = fminf(fminf(a[0],  a[1]),  a[2]);
    float m1 = fminf(fminf(a[3],  a[4]),  a[5]);
    float m2 = fminf(fminf(a[6],  a[7]),  a[8]);
    float m3 = fminf(fminf(a[9],  a[10]), a[11]);
    float m4 = fminf(fminf(a[12], a[13]), a[14]);
    float n0 = fminf(fminf(m0, m1), m2);
    float n1 = fminf(fminf(m3, m4), a[15]);
    return fminf(run, fminf(n0, n1));
}

// ---------------------------------------------------------------------------
// k-order (Q row must match R's subtiled khalf split):
//   k 0..5 : Q = ch0,ch1,ch2, cl0,cl1,cl2      R = mh0,mh1,mh2, mh0,mh1,mh2
//   k 6..7 : Q = n2h, n2l                       R = ONE, ONE
//   k 8..13: Q = ch0,ch1,ch2, cl0,cl1,cl2      R = ml0,ml1,ml2, ml0,ml1,ml2
//   k14..15: Q = ONE, ONE                       R = n2h, n2l
// Q_n . R_m = -2*(xh+xl).(yh+yl) + x2 + y2 ~= ||x-y||^2 (products exact;
// only hi/lo split residual ~2^-17 remains). Refs feed the MFMA A slot
// (lane-local min over C rows), queries the B slot (col=lane).
// Qpan: [cloud][PTOT][16] row-major. Rpan: [cloud][batch][tile][khalf][col][8].
// ---------------------------------------------------------------------------
__global__ __launch_bounds__(256) void pack_k(const float* __restrict__ pred,
                                              const float* __restrict__ tgt,
                                              ushort* __restrict__ Qpan,
                                              ushort* __restrict__ Rpan) {
    int i = blockIdx.x * 256 + threadIdx.x;      // [0, 2*PTOT), cloud-major
    int cloud = (i >= PTOT) ? 1 : 0;
    int jg = cloud ? i - PTOT : i;               // [0, PTOT)
    const float* s = cloud ? tgt : pred;
    float c0 = s[3 * jg + 0], c1 = s[3 * jg + 1], c2 = s[3 * jg + 2];
    float c[3] = {c0, c1, c2};
    ushort hh[3], ll[3], mh[3], ml[3];
#pragma unroll
    for (int d = 0; d < 3; ++d) {
        ushort h = f2bf(c[d]); float hf = bf2f(h);
        ushort l = f2bf(c[d] - hf); float lf = bf2f(l);   // exact residual split
        hh[d] = h; ll[d] = l;
        mh[d] = f2bf(-2.0f * hf);                         // exact (pow2 scale)
        ml[d] = f2bf(-2.0f * lf);
    }
    float n2 = fmaf(c0, c0, fmaf(c1, c1, c2 * c2));
    ushort n2h = f2bf(n2);
    ushort n2l = f2bf(n2 - bf2f(n2h));
    const ushort ONE = 0x3F80;

    __attribute__((aligned(16))) ushort a[16] = {
        hh[0], hh[1], hh[2], ll[0], ll[1], ll[2], n2h, n2l,
        hh[0], hh[1], hh[2], ll[0], ll[1], ll[2], ONE, ONE};
    __attribute__((aligned(16))) ushort blo[8] = {
        mh[0], mh[1], mh[2], mh[0], mh[1], mh[2], ONE, ONE};   // k = 0..7
    __attribute__((aligned(16))) ushort bhi[8] = {
        ml[0], ml[1], ml[2], ml[0], ml[1], ml[2], n2h, n2l};   // k = 8..15

    ushort* ad = Qpan + (size_t)i * 16;
    *(uint4*)ad       = *(const uint4*)a;
    *(uint4*)(ad + 8) = *(const uint4*)(a + 8);

    int loc = jg & (NPTS - 1);
    int t   = loc >> 5;
    int col = loc & 31;
    size_t bb = ((size_t)cloud * PTOT + (size_t)(jg >> 13) * NPTS) * 16
              + (size_t)t * 512 + (size_t)col * 8;
    *(uint4*)(Rpan + bb)       = *(const uint4*)blo;   // khalf 0
    *(uint4*)(Rpan + bb + 256) = *(const uint4*)bhi;   // khalf 1
}

// ---------------------------------------------------------------------------
// Best measured config (R15: 31.18us total). Grid: 1024 blocks = jh(8) x
// dir(2) x batch(4) x qblk(16); 512 thr (8 waves). __launch_bounds__(512, 4):
// 128-reg cap, no spills. Block stages its 32-tile ref panel (32 KB) into LDS
// once. Each wave: 64 queries (2 B-frags); per ref-tile: 1 ds_read_b128 ->
// 2 MFMA -> 2 tree16. Min is lane-local (C col=lane=query).
// part layout: [jh][dir][batch][NPTS].
// ---------------------------------------------------------------------------
__global__ __launch_bounds__(512, 4) void chamfer_mfma_k(const ushort* __restrict__ Qpan,
                                                         const ushort* __restrict__ Rpan,
                                                         float* __restrict__ part) {
    __shared__ ushort Rsm[TILES * 512];   // 32 KB

    int bid  = blockIdx.x;
    int qblk = bid & 15;
    int b    = (bid >> 4) & 3;
    int dir  = (bid >> 6) & 1;
    int jh   = bid >> 7;           // 0..7
    int tid  = threadIdx.x;
    int lane = tid & 63;
    int wave = tid >> 6;           // 0..7

    const ushort* Qp = Qpan + ((size_t)dir * PTOT + (size_t)b * NPTS) * 16;
    const ushort* Rp = Rpan + ((size_t)(1 - dir) * PTOT + (size_t)b * NPTS) * 16
                            + (size_t)jh * TILES * 512;

    // stage ref panel: 32 KB = 2048 float4, 512 threads x 4 iters (coalesced)
    {
        const float4* src = (const float4*)Rp;
        float4* dst = (float4*)Rsm;
#pragma unroll
        for (int it = 0; it < 4; ++it)
            dst[it * 512 + tid] = src[it * 512 + tid];
    }

    // Q frags (global, L2-resident): qf0 -> cols q..q+31, qf1 -> q+32..q+63
    int q = qblk * 512 + wave * 64;
    const short8 qf0 = *reinterpret_cast<const short8*>(
        Qp + (size_t)(q + (lane & 31)) * 16 + 8 * (lane >> 5));
    const short8 qf1 = *reinterpret_cast<const short8*>(
        Qp + (size_t)(q + 32 + (lane & 31)) * 16 + 8 * (lane >> 5));

    __syncthreads();

    // ref frag in LDS: tile t -> t*512 + (lane>>5)*256 + (lane&31)*8 (ushorts)
    const ushort* rbase = Rsm + (size_t)(lane >> 5) * 256 + (size_t)(lane & 31) * 8;

    f32x16 zero = {};
    float run0 = 1e30f, run1 = 1e30f;

#pragma unroll 8
    for (int t = 0; t < TILES; ++t) {
        short8 r = *reinterpret_cast<const short8*>(rbase + (size_t)t * 512);
        f32x16 a0 = __builtin_amdgcn_mfma_f32_32x32x16_bf16(r, qf0, zero, 0, 0, 0);
        f32x16 a1 = __builtin_amdgcn_mfma_f32_32x32x16_bf16(r, qf1, zero, 0, 0, 0);
        run0 = tree16(a0, run0);
        run1 = tree16(a1, run1);
    }

    // rows split across lane halves (row has +4*(lane>>5)): combine halves
    run0 = fminf(run0, __shfl_xor(run0, 32, 64));
    run1 = fminf(run1, __shfl_xor(run1, 32, 64));
    // lanes 0..31: queries q..q+31 (run0); lanes 32..63: q+32..q+63 (run1)
    size_t pbase = (((size_t)jh * 2 + dir) * BATCH + b) * NPTS;
    part[pbase + q + lane] = (lane < 32) ? run0 : run1;
}

// Stage 1: min over NJH splits, clamp, per-block sum (256 blocks).
__global__ __launch_bounds__(256) void reduce1_k(const float* __restrict__ part,
                                                 float* __restrict__ bsum) {
    int q = blockIdx.x * 256 + threadIdx.x;   // [0, 65536)
    float v = part[q];
#pragma unroll
    for (int jh = 1; jh < NJH; ++jh)
        v = fminf(v, part[(size_t)jh * 65536 + q]);
    v = fmaxf(v, 0.0f);
    for (int off = 32; off; off >>= 1) v += __shfl_down(v, off, 64);
    __shared__ float lds[4];
    int lane = threadIdx.x & 63, w = threadIdx.x >> 6;
    if (lane == 0) lds[w] = v;
    __syncthreads();
    if (threadIdx.x == 0)
        bsum[blockIdx.x] = (lds[0] + lds[1]) + (lds[2] + lds[3]);
}

// Stage 2: sum 256 block sums, scale.
__global__ __launch_bounds__(256) void reduce2_k(const float* __restrict__ bsum,
                                                 float* __restrict__ out) {
    float v = bsum[threadIdx.x];
    for (int off = 32; off; off >>= 1) v += __shfl_down(v, off, 64);
    __shared__ float lds[4];
    int lane = threadIdx.x & 63, w = threadIdx.x >> 6;
    if (lane == 0) lds[w] = v;
    __syncthreads();
    if (threadIdx.x == 0)
        out[0] = ((lds[0] + lds[1]) + (lds[2] + lds[3])) * (1.0f / 32768.0f);
}

extern "C" void kernel_launch(void* const* d_in, const int* in_sizes, int n_in,
                              void* d_out, int out_size, void* d_ws, size_t ws_size,
                              hipStream_t stream) {
    const float* pred = (const float*)d_in[0];
    const float* tgt  = (const float*)d_in[1];

    ushort* Qpan = (ushort*)d_ws;                          // 2 MB
    ushort* Rpan = Qpan + (size_t)2 * PTOT * 16;           // 2 MB
    float*  part = (float*)(Rpan + (size_t)2 * PTOT * 16); // NJH*2*PTOT floats = 2 MB
    float*  bsum = part + (size_t)NJH * 2 * PTOT;          // 256 floats

    pack_k<<<(2 * PTOT) / 256, 256, 0, stream>>>(pred, tgt, Qpan, Rpan);
    chamfer_mfma_k<<<NJH * 2 * BATCH * 16, 512, 0, stream>>>(Qpan, Rpan, part);
    reduce1_k<<<256, 256, 0, stream>>>(part, bsum);
    reduce2_k<<<1, 256, 0, stream>>>(bsum, (float*)d_out);
}